// Round 2
// baseline (779.084 us; speedup 1.0000x reference)
//
#include <hip/hip_runtime.h>

#define N_NODES 100000
#define N_EDGES 20000
#define N_INC   800000
#define D_IN    256
#define D_H     16
#define D_OUT   40

// ---------------- GEMM1: T = H @ W1  (shrink d 256 -> 16 BEFORE any scatter) ----
__global__ __launch_bounds__(128) void gemm1_kernel(
    const float* __restrict__ H, const float* __restrict__ W1, float* __restrict__ T) {
    int n = blockIdx.x * 128 + threadIdx.x;
    if (n >= N_NODES) return;
    const float4* __restrict__ h4 = reinterpret_cast<const float4*>(H) + (size_t)n * (D_IN / 4);
    float acc[D_H];
#pragma unroll
    for (int j = 0; j < D_H; ++j) acc[j] = 0.f;
#pragma unroll 4
    for (int k4 = 0; k4 < D_IN / 4; ++k4) {
        float4 h = h4[k4];
        const float* __restrict__ w0 = W1 + (k4 * 4 + 0) * D_H;
        const float* __restrict__ w1 = W1 + (k4 * 4 + 1) * D_H;
        const float* __restrict__ w2 = W1 + (k4 * 4 + 2) * D_H;
        const float* __restrict__ w3 = W1 + (k4 * 4 + 3) * D_H;
#pragma unroll
        for (int j = 0; j < D_H; ++j)
            acc[j] += h.x * w0[j] + h.y * w1[j] + h.z * w2[j] + h.w * w3[j];
    }
    float4* out4 = reinterpret_cast<float4*>(T + (size_t)n * D_H);
    out4[0] = make_float4(acc[0], acc[1], acc[2], acc[3]);
    out4[1] = make_float4(acc[4], acc[5], acc[6], acc[7]);
    out4[2] = make_float4(acc[8], acc[9], acc[10], acc[11]);
    out4[3] = make_float4(acc[12], acc[13], acc[14], acc[15]);
}

// ---------------- CSR build: histogram -> scan -> perm scatter ------------------
__global__ __launch_bounds__(256) void hist_kernel(
    const int* __restrict__ ni, const int* __restrict__ ei,
    int* __restrict__ cnt_e, int* __restrict__ cnt_v) {
    int i = blockIdx.x * 256 + threadIdx.x;
    if (i >= N_INC) return;
    atomicAdd(&cnt_e[ei[i]], 1);
    atomicAdd(&cnt_v[ni[i]], 1);
}

// single-workgroup exclusive scan; off[0..n] gets prefix (off[n]=total),
// cur[] re-initialized to the exclusive prefix (scatter cursor).
__global__ __launch_bounds__(1024) void scan_kernel(int* cur, int* off, int n) {
    __shared__ int buf[1024];
    __shared__ int carry_s;
    int tid = threadIdx.x;
    if (tid == 0) carry_s = 0;
    __syncthreads();
    for (int base = 0; base < n; base += 1024) {
        int c = carry_s;               // read BEFORE anyone updates it this chunk
        int i = base + tid;
        int v = (i < n) ? cur[i] : 0;
        buf[tid] = v;
        __syncthreads();
        for (int ofs = 1; ofs < 1024; ofs <<= 1) {
            int t = (tid >= ofs) ? buf[tid - ofs] : 0;
            __syncthreads();
            buf[tid] += t;
            __syncthreads();
        }
        int excl = buf[tid] - v + c;
        if (i < n) { off[i] = excl; cur[i] = excl; }
        __syncthreads();
        if (tid == 1023) carry_s = c + buf[1023];
        __syncthreads();
    }
    if (threadIdx.x == 0) off[n] = carry_s;
}

__global__ __launch_bounds__(256) void permscatter_kernel(
    const int* __restrict__ ni, const int* __restrict__ ei,
    int* __restrict__ cur_e, int* __restrict__ cur_v,
    int* __restrict__ perm_e, int* __restrict__ perm_v) {
    int i = blockIdx.x * 256 + threadIdx.x;
    if (i >= N_INC) return;
    int pe = atomicAdd(&cur_e[ei[i]], 1);
    perm_e[pe] = i;
    int pv = atomicAdd(&cur_v[ni[i]], 1);
    perm_v[pv] = i;
}

// ---------------- gatherA: node -> edge, one wave per edge ----------------------
// wave layout: lane = s*16 + j  (4 incidence slots x 16 features)
// writes normalized e_feat directly (den reduced in-register).
__global__ __launch_bounds__(256) void gatherA_kernel(
    const int* __restrict__ off_e, const int* __restrict__ perm_e,
    const int* __restrict__ ni, const float* __restrict__ w,
    const float* __restrict__ X, float* __restrict__ e_feat) {
    int e = (blockIdx.x * 256 + threadIdx.x) >> 6;
    if (e >= N_EDGES) return;
    int lane = threadIdx.x & 63;
    int s = lane >> 4, j = lane & 15;
    int beg = off_e[e], end = off_e[e + 1];
    float acc = 0.f, den = 0.f;
    for (int k = beg + s; k < end; k += 4) {
        int i = perm_e[k];
        int v = ni[i];
        float wv = w[v];
        acc += X[v * D_H + j] * wv;
        den += wv;
    }
    acc += __shfl_xor(acc, 16, 64);  den += __shfl_xor(den, 16, 64);
    acc += __shfl_xor(acc, 32, 64);  den += __shfl_xor(den, 32, 64);
    if (s == 0) e_feat[e * D_H + j] = acc / fmaxf(den, 1e-6f);
}

// ---------------- gatherB: edge -> node, 16 lanes per node ----------------------
// LAYER==1: fuse  *inv_deg + b1, relu  -> x1
// LAYER==2: write v_feat = acc*inv_deg (matmul+log_softmax in final_kernel)
template <int LAYER>
__global__ __launch_bounds__(256) void gatherB_kernel(
    const int* __restrict__ off_v, const int* __restrict__ perm_v,
    const int* __restrict__ ei, const float* __restrict__ e_feat,
    const float* __restrict__ b1, float* __restrict__ out) {
    int t = blockIdx.x * 256 + threadIdx.x;
    int n = t >> 4;
    if (n >= N_NODES) return;
    int j = t & 15;
    int beg = off_v[n], end = off_v[n + 1];
    float acc = 0.f;
    for (int k = beg; k < end; ++k) {
        int e = ei[perm_v[k]];
        acc += e_feat[e * D_H + j];
    }
    float inv = 1.f / fmaxf((float)(end - beg), 1.f);
    if (LAYER == 1)
        out[n * D_H + j] = fmaxf(acc * inv + b1[j], 0.f);
    else
        out[n * D_H + j] = acc * inv;
}

// ---------------- final: z = v2 @ W2 + b2 ; log_softmax -------------------------
__global__ __launch_bounds__(256) void final_kernel(
    const float* __restrict__ v2, const float* __restrict__ W2,
    const float* __restrict__ b2, float* __restrict__ out) {
    int n = blockIdx.x * 256 + threadIdx.x;
    if (n >= N_NODES) return;
    const float4* vs4 = reinterpret_cast<const float4*>(v2 + (size_t)n * D_H);
    float y[D_H];
    float4 a = vs4[0], b = vs4[1], c4 = vs4[2], d4 = vs4[3];
    y[0] = a.x;  y[1] = a.y;  y[2] = a.z;  y[3] = a.w;
    y[4] = b.x;  y[5] = b.y;  y[6] = b.z;  y[7] = b.w;
    y[8] = c4.x; y[9] = c4.y; y[10] = c4.z; y[11] = c4.w;
    y[12] = d4.x; y[13] = d4.y; y[14] = d4.z; y[15] = d4.w;

    float z[D_OUT];
#pragma unroll
    for (int c = 0; c < D_OUT; ++c) {
        float acc = b2[c];
#pragma unroll
        for (int j = 0; j < D_H; ++j) acc += y[j] * W2[j * D_OUT + c];
        z[c] = acc;
    }
    float m = z[0];
#pragma unroll
    for (int c = 1; c < D_OUT; ++c) m = fmaxf(m, z[c]);
    float se = 0.f;
#pragma unroll
    for (int c = 0; c < D_OUT; ++c) se += __expf(z[c] - m);
    float lse = m + __logf(se);
    float* o = out + (size_t)n * D_OUT;
#pragma unroll
    for (int c = 0; c < D_OUT; ++c) o[c] = z[c] - lse;
}

extern "C" void kernel_launch(void* const* d_in, const int* in_sizes, int n_in,
                              void* d_out, int out_size, void* d_ws, size_t ws_size,
                              hipStream_t stream) {
    const float* H  = (const float*)d_in[0];
    const float* w  = (const float*)d_in[1];
    const int*   ni = (const int*)d_in[2];
    const int*   ei = (const int*)d_in[3];
    const float* W1 = (const float*)d_in[4];
    const float* b1 = (const float*)d_in[5];
    const float* W2 = (const float*)d_in[6];
    const float* b2 = (const float*)d_in[7];
    float* out = (float*)d_out;

    // workspace layout (4-byte words)
    int*   ws_i   = (int*)d_ws;
    int*   cur_e  = ws_i + 0;         // 20000   (histogram, then cursor)
    int*   cur_v  = ws_i + 20000;     // 100000
    int*   off_e  = ws_i + 120000;    // 20001
    int*   off_v  = ws_i + 140004;    // 100001
    int*   perm_e = ws_i + 240008;    // 800000
    int*   perm_v = ws_i + 1040008;   // 800000
    float* T      = (float*)(ws_i + 1840008);  // 1600000 (16B aligned)
    float* e_feat = (float*)(ws_i + 3440008);  // 320000
    float* x1     = (float*)(ws_i + 3760008);  // 1600000
    float* v2     = (float*)(ws_i + 5360008);  // 1600000
    // total 6,960,008 words = 27.8 MB

    hipMemsetAsync(cur_e, 0, 120000 * sizeof(int), stream);  // cur_e + cur_v

    gemm1_kernel<<<(N_NODES + 127) / 128, 128, 0, stream>>>(H, W1, T);

    const int inc_grid = (N_INC + 255) / 256;
    hist_kernel<<<inc_grid, 256, 0, stream>>>(ni, ei, cur_e, cur_v);
    scan_kernel<<<1, 1024, 0, stream>>>(cur_e, off_e, N_EDGES);
    scan_kernel<<<1, 1024, 0, stream>>>(cur_v, off_v, N_NODES);
    permscatter_kernel<<<inc_grid, 256, 0, stream>>>(ni, ei, cur_e, cur_v, perm_e, perm_v);

    const int gA_grid = (N_EDGES * 64 + 255) / 256;     // 1 wave / edge
    const int gB_grid = (N_NODES * 16 + 255) / 256;     // 16 lanes / node

    // layer 1
    gatherA_kernel<<<gA_grid, 256, 0, stream>>>(off_e, perm_e, ni, w, T, e_feat);
    gatherB_kernel<1><<<gB_grid, 256, 0, stream>>>(off_v, perm_v, ei, e_feat, b1, x1);
    // layer 2
    gatherA_kernel<<<gA_grid, 256, 0, stream>>>(off_e, perm_e, ni, w, x1, e_feat);
    gatherB_kernel<2><<<gB_grid, 256, 0, stream>>>(off_v, perm_v, ei, e_feat, b1, v2);

    final_kernel<<<(N_NODES + 255) / 256, 256, 0, stream>>>(v2, W2, b2, out);
}

// Round 3
// 568.308 us; speedup vs baseline: 1.3709x; 1.3709x over previous
//
#include <hip/hip_runtime.h>

#define N_NODES 100000
#define N_EDGES 20000
#define N_INC   800000
#define D_IN    256
#define D_H     16
#define D_OUT   40

// ---------------- GEMM1: T = H @ W1  (shrink d 256 -> 16 BEFORE any gather) ----
__global__ __launch_bounds__(128) void gemm1_kernel(
    const float* __restrict__ H, const float* __restrict__ W1, float* __restrict__ T) {
    int n = blockIdx.x * 128 + threadIdx.x;
    if (n >= N_NODES) return;
    const float4* __restrict__ h4 = reinterpret_cast<const float4*>(H) + (size_t)n * (D_IN / 4);
    float acc[D_H];
#pragma unroll
    for (int j = 0; j < D_H; ++j) acc[j] = 0.f;
#pragma unroll 4
    for (int k4 = 0; k4 < D_IN / 4; ++k4) {
        float4 h = h4[k4];
        const float* __restrict__ w0 = W1 + (k4 * 4 + 0) * D_H;
        const float* __restrict__ w1 = W1 + (k4 * 4 + 1) * D_H;
        const float* __restrict__ w2 = W1 + (k4 * 4 + 2) * D_H;
        const float* __restrict__ w3 = W1 + (k4 * 4 + 3) * D_H;
#pragma unroll
        for (int j = 0; j < D_H; ++j)
            acc[j] += h.x * w0[j] + h.y * w1[j] + h.z * w2[j] + h.w * w3[j];
    }
    float4* out4 = reinterpret_cast<float4*>(T + (size_t)n * D_H);
    out4[0] = make_float4(acc[0], acc[1], acc[2], acc[3]);
    out4[1] = make_float4(acc[4], acc[5], acc[6], acc[7]);
    out4[2] = make_float4(acc[8], acc[9], acc[10], acc[11]);
    out4[3] = make_float4(acc[12], acc[13], acc[14], acc[15]);
}

// ---------------- CSR build: histogram -> scan -> perm scatter ------------------
__global__ __launch_bounds__(256) void hist_kernel(
    const int* __restrict__ ni, const int* __restrict__ ei,
    int* __restrict__ cnt_e, int* __restrict__ cnt_v) {
    int i = blockIdx.x * 256 + threadIdx.x;
    if (i >= N_INC) return;
    atomicAdd(&cnt_e[ei[i]], 1);
    atomicAdd(&cnt_v[ni[i]], 1);
}

// One kernel, 2 blocks: block 0 scans the edge histogram, block 1 the node
// histogram (concurrent on different CUs). Chunk-per-thread serial scan:
// serial sum -> single block scan of 1024 sums -> serial prefix writeback.
// chunk is a multiple of 4 and n%4==0, so pure int4 loops are exact.
__global__ __launch_bounds__(1024) void scan2_kernel(
    int* __restrict__ cur_e, int* __restrict__ off_e,
    int* __restrict__ cur_v, int* __restrict__ off_v) {
    int* cur; int* off; int n;
    if (blockIdx.x == 0) { cur = cur_e; off = off_e; n = N_EDGES; }
    else                 { cur = cur_v; off = off_v; n = N_NODES; }
    int tid = threadIdx.x;
    int chunk = ((n + 1023) / 1024 + 3) & ~3;
    int beg = min(tid * chunk, n);
    int end = min(beg + chunk, n);
    int sum = 0;
    for (int i = beg; i + 3 < end; i += 4) {
        int4 v = *(const int4*)(cur + i);
        sum += v.x + v.y + v.z + v.w;
    }
    __shared__ int wsum[16];
    int lane = tid & 63, wid = tid >> 6;
    int s = sum;
#pragma unroll
    for (int ofs = 1; ofs < 64; ofs <<= 1) {
        int t = __shfl_up(s, ofs, 64);
        if (lane >= ofs) s += t;
    }
    if (lane == 63) wsum[wid] = s;
    __syncthreads();
    if (tid < 64) {
        int v = (lane < 16) ? wsum[lane] : 0;
#pragma unroll
        for (int ofs = 1; ofs < 16; ofs <<= 1) {
            int t = __shfl_up(v, ofs, 64);
            if (lane >= ofs) v += t;
        }
        if (lane < 16) wsum[lane] = v;   // inclusive scan of wave sums
    }
    __syncthreads();
    int run = s - sum + (wid ? wsum[wid - 1] : 0);   // exclusive prefix
    for (int i = beg; i + 3 < end; i += 4) {
        int4 v = *(const int4*)(cur + i);
        int4 o;
        o.x = run; run += v.x;
        o.y = run; run += v.y;
        o.z = run; run += v.z;
        o.w = run; run += v.w;
        *(int4*)(off + i) = o;
        *(int4*)(cur + i) = o;
    }
    if (tid == 1023) off[n] = run;   // tid 1023 has empty chunk -> run == total
}

// Pre-dereference: store ni[i], w[ni[i]] in edge-CSR order and ei[i] in
// node-CSR order, so the hot gathers have a 1-deep load chain.
__global__ __launch_bounds__(256) void permscatter_kernel(
    const int* __restrict__ ni, const int* __restrict__ ei, const float* __restrict__ w,
    int* __restrict__ cur_e, int* __restrict__ cur_v,
    int* __restrict__ nidx_e, float* __restrict__ wts_e, int* __restrict__ eidx_v) {
    int i = blockIdx.x * 256 + threadIdx.x;
    if (i >= N_INC) return;
    int v = ni[i], e = ei[i];
    int pe = atomicAdd(&cur_e[e], 1);
    nidx_e[pe] = v;
    wts_e[pe] = w[v];
    int pv = atomicAdd(&cur_v[v], 1);
    eidx_v[pv] = e;
}

// ---------------- gatherA: node -> edge, one wave per edge ----------------------
// lane = s*16 + j (4 incidence slots x 16 features); writes normalized e_feat.
__global__ __launch_bounds__(256) void gatherA_kernel(
    const int* __restrict__ off_e, const int* __restrict__ nidx_e,
    const float* __restrict__ wts_e,
    const float* __restrict__ X, float* __restrict__ e_feat) {
    int e = (blockIdx.x * 256 + threadIdx.x) >> 6;
    if (e >= N_EDGES) return;
    int lane = threadIdx.x & 63;
    int s = lane >> 4, j = lane & 15;
    int beg = off_e[e], end = off_e[e + 1];
    float acc = 0.f, den = 0.f;
    for (int k = beg + s; k < end; k += 4) {
        int v = nidx_e[k];
        float wv = wts_e[k];
        acc += X[v * D_H + j] * wv;
        den += wv;
    }
    acc += __shfl_xor(acc, 16, 64);  den += __shfl_xor(den, 16, 64);
    acc += __shfl_xor(acc, 32, 64);  den += __shfl_xor(den, 32, 64);
    if (s == 0) e_feat[e * D_H + j] = acc / fmaxf(den, 1e-6f);
}

// ---------------- gatherB: edge -> node, 16 lanes per node ----------------------
template <int LAYER>
__global__ __launch_bounds__(256) void gatherB_kernel(
    const int* __restrict__ off_v, const int* __restrict__ eidx_v,
    const float* __restrict__ e_feat,
    const float* __restrict__ b1, float* __restrict__ out) {
    int t = blockIdx.x * 256 + threadIdx.x;
    int n = t >> 4;
    if (n >= N_NODES) return;
    int j = t & 15;
    int beg = off_v[n], end = off_v[n + 1];
    float acc = 0.f;
    for (int k = beg; k < end; ++k) {
        int e = eidx_v[k];
        acc += e_feat[e * D_H + j];
    }
    float inv = 1.f / fmaxf((float)(end - beg), 1.f);
    if (LAYER == 1)
        out[n * D_H + j] = fmaxf(acc * inv + b1[j], 0.f);
    else
        out[n * D_H + j] = acc * inv;
}

// ---------------- final: z = v2 @ W2 + b2 ; log_softmax -------------------------
__global__ __launch_bounds__(256) void final_kernel(
    const float* __restrict__ v2, const float* __restrict__ W2,
    const float* __restrict__ b2, float* __restrict__ out) {
    int n = blockIdx.x * 256 + threadIdx.x;
    if (n >= N_NODES) return;
    const float4* vs4 = reinterpret_cast<const float4*>(v2 + (size_t)n * D_H);
    float y[D_H];
    float4 a = vs4[0], b = vs4[1], c4 = vs4[2], d4 = vs4[3];
    y[0] = a.x;  y[1] = a.y;  y[2] = a.z;  y[3] = a.w;
    y[4] = b.x;  y[5] = b.y;  y[6] = b.z;  y[7] = b.w;
    y[8] = c4.x; y[9] = c4.y; y[10] = c4.z; y[11] = c4.w;
    y[12] = d4.x; y[13] = d4.y; y[14] = d4.z; y[15] = d4.w;

    float z[D_OUT];
#pragma unroll
    for (int c = 0; c < D_OUT; ++c) {
        float acc = b2[c];
#pragma unroll
        for (int j = 0; j < D_H; ++j) acc += y[j] * W2[j * D_OUT + c];
        z[c] = acc;
    }
    float m = z[0];
#pragma unroll
    for (int c = 1; c < D_OUT; ++c) m = fmaxf(m, z[c]);
    float se = 0.f;
#pragma unroll
    for (int c = 0; c < D_OUT; ++c) se += __expf(z[c] - m);
    float lse = m + __logf(se);
    float* o = out + (size_t)n * D_OUT;
#pragma unroll
    for (int c = 0; c < D_OUT; ++c) o[c] = z[c] - lse;
}

extern "C" void kernel_launch(void* const* d_in, const int* in_sizes, int n_in,
                              void* d_out, int out_size, void* d_ws, size_t ws_size,
                              hipStream_t stream) {
    const float* H  = (const float*)d_in[0];
    const float* w  = (const float*)d_in[1];
    const int*   ni = (const int*)d_in[2];
    const int*   ei = (const int*)d_in[3];
    const float* W1 = (const float*)d_in[4];
    const float* b1 = (const float*)d_in[5];
    const float* W2 = (const float*)d_in[6];
    const float* b2 = (const float*)d_in[7];
    float* out = (float*)d_out;

    // workspace layout (4-byte words); all int4/float4 users 16B-aligned
    int*   ws_i   = (int*)d_ws;
    int*   cur_e  = ws_i + 0;                  // 20000 (hist, then cursor)
    int*   cur_v  = ws_i + 20000;              // 100000
    int*   off_e  = ws_i + 120000;             // 20001
    int*   off_v  = ws_i + 140004;             // 100001
    int*   nidx_e = ws_i + 240008;             // 800000
    float* wts_e  = (float*)(ws_i + 1040008);  // 800000
    int*   eidx_v = ws_i + 1840008;            // 800000
    float* T      = (float*)(ws_i + 2640008);  // 1600000 (reused as v2)
    float* e_feat = (float*)(ws_i + 4240008);  // 320000
    float* x1     = (float*)(ws_i + 4560008);  // 1600000
    float* v2     = T;                         // T dead after layer-1 gatherA
    // total 6,160,008 words = 24.6 MB

    hipMemsetAsync(cur_e, 0, 120000 * sizeof(int), stream);  // cur_e + cur_v

    gemm1_kernel<<<(N_NODES + 127) / 128, 128, 0, stream>>>(H, W1, T);

    const int inc_grid = (N_INC + 255) / 256;
    hist_kernel<<<inc_grid, 256, 0, stream>>>(ni, ei, cur_e, cur_v);
    scan2_kernel<<<2, 1024, 0, stream>>>(cur_e, off_e, cur_v, off_v);
    permscatter_kernel<<<inc_grid, 256, 0, stream>>>(ni, ei, w, cur_e, cur_v,
                                                     nidx_e, wts_e, eidx_v);

    const int gA_grid = (N_EDGES * 64 + 255) / 256;     // 1 wave / edge
    const int gB_grid = (N_NODES * 16 + 255) / 256;     // 16 lanes / node

    // layer 1
    gatherA_kernel<<<gA_grid, 256, 0, stream>>>(off_e, nidx_e, wts_e, T, e_feat);
    gatherB_kernel<1><<<gB_grid, 256, 0, stream>>>(off_v, eidx_v, e_feat, b1, x1);
    // layer 2
    gatherA_kernel<<<gA_grid, 256, 0, stream>>>(off_e, nidx_e, wts_e, x1, e_feat);
    gatherB_kernel<2><<<gB_grid, 256, 0, stream>>>(off_v, eidx_v, e_feat, b1, v2);

    final_kernel<<<(N_NODES + 255) / 256, 256, 0, stream>>>(v2, W2, b2, out);
}